// Round 1
// baseline (279.829 us; speedup 1.0000x reference)
//
#include <hip/hip_runtime.h>

typedef float  floatx4 __attribute__((ext_vector_type(4)));
typedef _Float16 half8 __attribute__((ext_vector_type(8)));
typedef _Float16 half4v __attribute__((ext_vector_type(4)));
typedef _Float16 half2v __attribute__((ext_vector_type(2)));

__device__ __forceinline__ void gld16(const void* g, void* l) {
    __builtin_amdgcn_global_load_lds(
        (const __attribute__((address_space(1))) void*)g,
        (__attribute__((address_space(3))) void*)l, 16, 0, 0);
}

// ---------------------------------------------------------------- conv x f32->f16
__global__ __launch_bounds__(256) void conv_x_kernel(const float* __restrict__ x,
                                                     _Float16* __restrict__ xh) {
    int i = blockIdx.x * 256 + threadIdx.x;   // one float4 per thread, 1M threads
    float4 v = ((const float4*)x)[i];
    half4v o = { (_Float16)v.x, (_Float16)v.y, (_Float16)v.z, (_Float16)v.w };
    ((half4v*)xh)[i] = o;
}

// ------------------------------------------------- transpose f32 [K][N] -> f16 [N][K]
__global__ __launch_bounds__(256) void transpose_f32f16(const float* __restrict__ W,
                                                        _Float16* __restrict__ WT,
                                                        int K, int N) {
    __shared__ _Float16 t[64][72];
    int n0 = blockIdx.x * 64, k0 = blockIdx.y * 64;
    int c = threadIdx.x & 63, r4 = threadIdx.x >> 6;
    for (int rr = 0; rr < 64; rr += 4) {
        int k = k0 + rr + r4;
        t[rr + r4][c] = (_Float16)W[(size_t)k * N + n0 + c];
    }
    __syncthreads();
    for (int rr = 0; rr < 64; rr += 4) {
        int n = n0 + rr + r4;
        WT[(size_t)n * K + k0 + c] = t[c][rr + r4];
    }
}

// ---------------------------------------------------------------- GEMM (A[M][K] x BT[N][K])
// 128x128 tile, BK=32, 256 threads (4 waves, 2x2 of 64x64), global_load_lds staging.
__global__ __launch_bounds__(256) void gemm_tn(const _Float16* __restrict__ A,
                                               const _Float16* __restrict__ BT,
                                               _Float16* __restrict__ Cf16,
                                               float* __restrict__ Cf32,
                                               int M, int N, int K) {
    __shared__ __align__(16) _Float16 sA[128 * 32];
    __shared__ __align__(16) _Float16 sB[128 * 32];

    const int tid  = threadIdx.x;
    const int wave = tid >> 6, lane = tid & 63;
    const int lrow = lane & 15, quad = lane >> 4;
    const int bm = blockIdx.x * 128, bn = blockIdx.y * 128;
    const int waveM = (wave >> 1) * 64, waveN = (wave & 1) * 64;

    floatx4 acc[4][4] = {};

    // staging: 512 chunks of 16B per matrix; thread handles chunk tid and tid+256
    const int r0 = tid >> 2,          k80 = (tid & 3) * 8;
    const int r1 = (tid + 256) >> 2,  k81 = ((tid + 256) & 3) * 8;
    _Float16* lA0 = sA + (wave * 64) * 8;
    _Float16* lA1 = sA + (wave * 64 + 256) * 8;
    _Float16* lB0 = sB + (wave * 64) * 8;
    _Float16* lB1 = sB + (wave * 64 + 256) * 8;
    const _Float16* A0 = A + (size_t)(bm + r0) * K + k80;
    const _Float16* A1 = A + (size_t)(bm + r1) * K + k81;
    const _Float16* B0 = BT + (size_t)(bn + r0) * K + k80;
    const _Float16* B1 = BT + (size_t)(bn + r1) * K + k81;

    for (int k0 = 0; k0 < K; k0 += 32) {
        gld16(A0 + k0, lA0);
        gld16(A1 + k0, lA1);
        gld16(B0 + k0, lB0);
        gld16(B1 + k0, lB1);
        __syncthreads();

        half8 aF[4], bF[4];
#pragma unroll
        for (int mt = 0; mt < 4; ++mt)
            aF[mt] = *(const half8*)&sA[(waveM + mt * 16 + lrow) * 32 + quad * 8];
#pragma unroll
        for (int nt = 0; nt < 4; ++nt)
            bF[nt] = *(const half8*)&sB[(waveN + nt * 16 + lrow) * 32 + quad * 8];
#pragma unroll
        for (int mt = 0; mt < 4; ++mt)
#pragma unroll
            for (int nt = 0; nt < 4; ++nt)
                acc[mt][nt] = __builtin_amdgcn_mfma_f32_16x16x32_f16(
                    aF[mt], bF[nt], acc[mt][nt], 0, 0, 0);
        __syncthreads();
    }

#pragma unroll
    for (int mt = 0; mt < 4; ++mt)
#pragma unroll
        for (int nt = 0; nt < 4; ++nt)
#pragma unroll
            for (int r = 0; r < 4; ++r) {
                int row = bm + waveM + mt * 16 + quad * 4 + r;
                int col = bn + waveN + nt * 16 + lrow;
                if (Cf16) Cf16[(size_t)row * N + col] = (_Float16)acc[mt][nt][r];
                else      Cf32[(size_t)row * N + col] = acc[mt][nt][r];
            }
}

// ---------------------------------------------------------------- RoPE + split q/k
// qkv f16 [4096][3072] -> qh, kh f16 [32][2048][64] with rotation applied
__global__ __launch_bounds__(256) void rope_split(const _Float16* __restrict__ qkv,
                                                  const float* __restrict__ fc,
                                                  const float* __restrict__ fs,
                                                  _Float16* __restrict__ qh,
                                                  _Float16* __restrict__ kh) {
    int row = blockIdx.x;           // 0..4095
    int b = row >> 11, t = row & 2047;
    const _Float16* src = qkv + (size_t)row * 3072;
    for (int p = threadIdx.x; p < 512; p += 256) {
        int h = p >> 5, j = p & 31;
        float c = fc[t * 32 + j], s = fs[t * 32 + j];
        size_t o = ((size_t)(b * 16 + h) * 2048 + t) * 64 + 2 * j;
        {
            half2v xin = *(const half2v*)&src[h * 64 + 2 * j];
            float x0 = (float)xin[0], x1 = (float)xin[1];
            half2v out = { (_Float16)(x0 * c - x1 * s), (_Float16)(x0 * s + x1 * c) };
            *(half2v*)&qh[o] = out;
        }
        {
            half2v xin = *(const half2v*)&src[1024 + h * 64 + 2 * j];
            float x0 = (float)xin[0], x1 = (float)xin[1];
            half2v out = { (_Float16)(x0 * c - x1 * s), (_Float16)(x0 * s + x1 * c) };
            *(half2v*)&kh[o] = out;
        }
    }
}

// ---------------------------------------------------------------- V transpose
// qkv f16 [4096][3072] (cols 2048..3071) -> vt f16 [32][64][2048]
__global__ __launch_bounds__(256) void vtrans(const _Float16* __restrict__ qkv,
                                              _Float16* __restrict__ vt) {
    __shared__ _Float16 s[64][72];
    int bh = blockIdx.y, t0 = blockIdx.x * 64;
    int b = bh >> 4, h = bh & 15;
    int c = threadIdx.x & 63, r4 = threadIdx.x >> 6;
    const _Float16* src = qkv + 2048 + h * 64;
    for (int rr = 0; rr < 64; rr += 4) {
        int t = t0 + rr + r4;
        s[rr + r4][c] = src[(size_t)(b * 2048 + t) * 3072 + c];
    }
    __syncthreads();
    for (int rr = 0; rr < 64; rr += 4) {
        int hd = rr + r4;
        vt[((size_t)bh * 64 + hd) * 2048 + t0 + c] = s[c][hd];
    }
}

// ---------------------------------------------------------------- flash attention
// Q,K: [32][2048][64], Vt: [32][64][2048], Y: [4096][1024]  (all f16)
// block = (q-tile of 64 rows) x (b,h); 4 waves, wave w owns q-rows w*16..w*16+15
__global__ __launch_bounds__(256) void attn64(const _Float16* __restrict__ Q,
                                              const _Float16* __restrict__ Kk,
                                              const _Float16* __restrict__ Vt,
                                              _Float16* __restrict__ Y) {
    __shared__ __align__(16) _Float16 sK[64 * 64];   // [key][hd], xor-swizzled 16B chunks
    __shared__ __align__(16) _Float16 sV[64 * 64];   // [hd][key], xor-swizzled
    __shared__ __align__(16) _Float16 sP[64 * 72];   // [qrow][key], padded

    const int bh = blockIdx.y;
    const int b = bh >> 4, h = bh & 15;
    const int qt = (int)gridDim.x - 1 - (int)blockIdx.x;   // heavy tiles dispatch first
    const int q0 = qt * 64;
    const int tid = threadIdx.x;
    const int wave = tid >> 6, lane = tid & 63;
    const int lrow = lane & 15, quad = lane >> 4;

    // Q fragments, scale 1/sqrt(64)=0.125 folded in (exact in f16)
    const _Float16* Qp = Q + ((size_t)bh * 2048 + q0 + wave * 16 + lrow) * 64;
    half8 qF[2];
#pragma unroll
    for (int ks = 0; ks < 2; ++ks) {
        half8 v = *(const half8*)(Qp + ks * 32 + quad * 8);
        qF[ks] = v * (_Float16)0.125f;
    }

    floatx4 O[4] = {};
    float m_i[4], l_i[4];
#pragma unroll
    for (int r = 0; r < 4; ++r) { m_i[r] = -1e30f; l_i[r] = 0.f; }

    const _Float16* Kbase = Kk + (size_t)bh * 2048 * 64;
    const _Float16* Vbase = Vt + (size_t)bh * 64 * 2048;

    for (int k0 = 0; k0 <= q0; k0 += 64) {
        // ---- stage K [64key][64hd] and V^T [64hd][64key], xor-swizzled chunks
        for (int c = tid; c < 512; c += 256) {
            int key = c >> 3, cc = c & 7;
            uint4 d = *(const uint4*)(Kbase + (size_t)(k0 + key) * 64 + cc * 8);
            *(uint4*)&sK[key * 64 + ((cc ^ (key & 7)) * 8)] = d;
        }
        for (int c = tid; c < 512; c += 256) {
            int hd = c >> 3, cc = c & 7;
            uint4 d = *(const uint4*)(Vbase + (size_t)hd * 2048 + k0 + cc * 8);
            *(uint4*)&sV[hd * 64 + ((cc ^ (hd & 7)) * 8)] = d;
        }
        __syncthreads();

        // ---- S = (Q*scale) K^T : wave's 16 q-rows x 64 keys
        floatx4 S[4];
#pragma unroll
        for (int kt4 = 0; kt4 < 4; ++kt4) {
            floatx4 s = {};
#pragma unroll
            for (int ks = 0; ks < 2; ++ks) {
                int key = kt4 * 16 + lrow;
                half8 kf = *(const half8*)&sK[key * 64 + (((ks * 4 + quad) ^ (lrow & 7)) * 8)];
                s = __builtin_amdgcn_mfma_f32_16x16x32_f16(qF[ks], kf, s, 0, 0, 0);
            }
            S[kt4] = s;
        }
        if (k0 == q0) {   // diagonal tile: causal mask
#pragma unroll
            for (int kt4 = 0; kt4 < 4; ++kt4)
#pragma unroll
                for (int r = 0; r < 4; ++r) {
                    int qrow = wave * 16 + quad * 4 + r;
                    int kcol = kt4 * 16 + lrow;
                    if (kcol > qrow) S[kt4][r] = -1e30f;
                }
        }

        // ---- online softmax (rows live at quad*4+r across 16 lanes)
        float alpha[4];
#pragma unroll
        for (int r = 0; r < 4; ++r) {
            float v = fmaxf(fmaxf(S[0][r], S[1][r]), fmaxf(S[2][r], S[3][r]));
            v = fmaxf(v, __shfl_xor(v, 1));
            v = fmaxf(v, __shfl_xor(v, 2));
            v = fmaxf(v, __shfl_xor(v, 4));
            v = fmaxf(v, __shfl_xor(v, 8));
            float mn = fmaxf(m_i[r], v);
            alpha[r] = __expf(m_i[r] - mn);
            m_i[r] = mn;
        }
#pragma unroll
        for (int kt4 = 0; kt4 < 4; ++kt4)
#pragma unroll
            for (int r = 0; r < 4; ++r)
                S[kt4][r] = __expf(S[kt4][r] - m_i[r]);
        float rs[4];
#pragma unroll
        for (int r = 0; r < 4; ++r) {
            float v = S[0][r] + S[1][r] + S[2][r] + S[3][r];
            v += __shfl_xor(v, 1);
            v += __shfl_xor(v, 2);
            v += __shfl_xor(v, 4);
            v += __shfl_xor(v, 8);
            rs[r] = v;
            l_i[r] = l_i[r] * alpha[r] + v;
        }

        // ---- P -> LDS (C/D layout -> A layout round trip), rescale O
#pragma unroll
        for (int kt4 = 0; kt4 < 4; ++kt4)
#pragma unroll
            for (int r = 0; r < 4; ++r)
                sP[(wave * 16 + quad * 4 + r) * 72 + kt4 * 16 + lrow] = (_Float16)S[kt4][r];
#pragma unroll
        for (int nt = 0; nt < 4; ++nt)
#pragma unroll
            for (int r = 0; r < 4; ++r)
                O[nt][r] *= alpha[r];

        // ---- O += P V
        half8 aP[2];
#pragma unroll
        for (int ks = 0; ks < 2; ++ks)
            aP[ks] = *(const half8*)&sP[(wave * 16 + lrow) * 72 + ks * 32 + quad * 8];
#pragma unroll
        for (int nt = 0; nt < 4; ++nt)
#pragma unroll
            for (int ks = 0; ks < 2; ++ks) {
                half8 vf = *(const half8*)&sV[(nt * 16 + lrow) * 64 +
                                              (((ks * 4 + quad) ^ (lrow & 7)) * 8)];
                O[nt] = __builtin_amdgcn_mfma_f32_16x16x32_f16(aP[ks], vf, O[nt], 0, 0, 0);
            }
        __syncthreads();
    }

    // ---- epilogue: O/l -> Y [B,T,H*HD]
#pragma unroll
    for (int r = 0; r < 4; ++r) {
        float inv = 1.0f / l_i[r];
        int q = q0 + wave * 16 + quad * 4 + r;
        size_t rowoff = ((size_t)b * 2048 + q) * 1024 + h * 64;
#pragma unroll
        for (int nt = 0; nt < 4; ++nt)
            Y[rowoff + nt * 16 + lrow] = (_Float16)(O[nt][r] * inv);
    }
}

// ---------------------------------------------------------------- launch
extern "C" void kernel_launch(void* const* d_in, const int* in_sizes, int n_in,
                              void* d_out, int out_size, void* d_ws, size_t ws_size,
                              hipStream_t stream) {
    const float* x     = (const float*)d_in[0];
    const float* wqkv  = (const float*)d_in[1];
    const float* wproj = (const float*)d_in[2];
    const float* fc    = (const float*)d_in[3];
    const float* fs    = (const float*)d_in[4];
    float* out = (float*)d_out;

    char* ws = (char*)d_ws;
    _Float16* xh   = (_Float16*)(ws);                       // 8 MB  (reused as yh)
    _Float16* wqT  = (_Float16*)(ws + ((size_t)8  << 20));  // 6 MB
    _Float16* wpT  = (_Float16*)(ws + ((size_t)14 << 20));  // 2 MB
    _Float16* qkvh = (_Float16*)(ws + ((size_t)16 << 20));  // 24 MB
    _Float16* qh   = (_Float16*)(ws + ((size_t)40 << 20));  // 8 MB
    _Float16* kh   = (_Float16*)(ws + ((size_t)48 << 20));  // 8 MB
    _Float16* vt   = (_Float16*)(ws + ((size_t)56 << 20));  // 8 MB
    _Float16* yh   = xh;   // x dead after gemm1

    conv_x_kernel<<<4096, 256, 0, stream>>>(x, xh);
    transpose_f32f16<<<dim3(48, 16), 256, 0, stream>>>(wqkv, wqT, 1024, 3072);
    transpose_f32f16<<<dim3(16, 16), 256, 0, stream>>>(wproj, wpT, 1024, 1024);
    gemm_tn<<<dim3(32, 24), 256, 0, stream>>>(xh, wqT, qkvh, nullptr, 4096, 3072, 1024);
    rope_split<<<4096, 256, 0, stream>>>(qkvh, fc, fs, qh, kh);
    vtrans<<<dim3(32, 32), 256, 0, stream>>>(qkvh, vt);
    attn64<<<dim3(32, 32), 256, 0, stream>>>(qh, kh, vt, yh);
    gemm_tn<<<dim3(32, 8), 256, 0, stream>>>(yh, wpT, nullptr, out, 4096, 1024, 1024);
}

// Round 3
// 219.449 us; speedup vs baseline: 1.2751x; 1.2751x over previous
//
#include <hip/hip_runtime.h>

typedef float  floatx4 __attribute__((ext_vector_type(4)));
typedef _Float16 half8 __attribute__((ext_vector_type(8)));
typedef _Float16 half4v __attribute__((ext_vector_type(4)));
typedef _Float16 half2v __attribute__((ext_vector_type(2)));

__device__ __forceinline__ void gld16(const void* g, void* l) {
    __builtin_amdgcn_global_load_lds(
        (const __attribute__((address_space(1))) void*)g,
        (__attribute__((address_space(3))) void*)l, 16, 0, 0);
}

// ---------------------------------------------------------------- conv x f32->f16
__global__ __launch_bounds__(256) void conv_x_kernel(const float* __restrict__ x,
                                                     _Float16* __restrict__ xh) {
    int i = blockIdx.x * 256 + threadIdx.x;
    float4 v = ((const float4*)x)[i];
    half4v o = { (_Float16)v.x, (_Float16)v.y, (_Float16)v.z, (_Float16)v.w };
    ((half4v*)xh)[i] = o;
}

// ------------------------------------------------- transpose f32 [K][N] -> f16 [N][K]
__global__ __launch_bounds__(256) void transpose_f32f16(const float* __restrict__ W,
                                                        _Float16* __restrict__ WT,
                                                        int K, int N) {
    __shared__ _Float16 t[64][72];
    int n0 = blockIdx.x * 64, k0 = blockIdx.y * 64;
    int c = threadIdx.x & 63, r4 = threadIdx.x >> 6;
    for (int rr = 0; rr < 64; rr += 4) {
        int k = k0 + rr + r4;
        t[rr + r4][c] = (_Float16)W[(size_t)k * N + n0 + c];
    }
    __syncthreads();
    for (int rr = 0; rr < 64; rr += 4) {
        int n = n0 + rr + r4;
        WT[(size_t)n * K + k0 + c] = t[c][rr + r4];
    }
}

// ---------------------------------------------------------------- GEMM (A[M][K] x BT[N][K])
__global__ __launch_bounds__(256) void gemm_tn(const _Float16* __restrict__ A,
                                               const _Float16* __restrict__ BT,
                                               _Float16* __restrict__ Cf16,
                                               float* __restrict__ Cf32,
                                               int M, int N, int K) {
    __shared__ __align__(16) _Float16 sA[128 * 32];
    __shared__ __align__(16) _Float16 sB[128 * 32];

    const int tid  = threadIdx.x;
    const int wave = tid >> 6, lane = tid & 63;
    const int lrow = lane & 15, quad = lane >> 4;
    const int bm = blockIdx.x * 128, bn = blockIdx.y * 128;
    const int waveM = (wave >> 1) * 64, waveN = (wave & 1) * 64;

    floatx4 acc[4][4] = {};

    const int r0 = tid >> 2,          k80 = (tid & 3) * 8;
    const int r1 = (tid + 256) >> 2,  k81 = ((tid + 256) & 3) * 8;
    _Float16* lA0 = sA + (wave * 64) * 8;
    _Float16* lA1 = sA + (wave * 64 + 256) * 8;
    _Float16* lB0 = sB + (wave * 64) * 8;
    _Float16* lB1 = sB + (wave * 64 + 256) * 8;
    const _Float16* A0 = A + (size_t)(bm + r0) * K + k80;
    const _Float16* A1 = A + (size_t)(bm + r1) * K + k81;
    const _Float16* B0 = BT + (size_t)(bn + r0) * K + k80;
    const _Float16* B1 = BT + (size_t)(bn + r1) * K + k81;

    for (int k0 = 0; k0 < K; k0 += 32) {
        gld16(A0 + k0, lA0);
        gld16(A1 + k0, lA1);
        gld16(B0 + k0, lB0);
        gld16(B1 + k0, lB1);
        __syncthreads();

        half8 aF[4], bF[4];
#pragma unroll
        for (int mt = 0; mt < 4; ++mt)
            aF[mt] = *(const half8*)&sA[(waveM + mt * 16 + lrow) * 32 + quad * 8];
#pragma unroll
        for (int nt = 0; nt < 4; ++nt)
            bF[nt] = *(const half8*)&sB[(waveN + nt * 16 + lrow) * 32 + quad * 8];
#pragma unroll
        for (int mt = 0; mt < 4; ++mt)
#pragma unroll
            for (int nt = 0; nt < 4; ++nt)
                acc[mt][nt] = __builtin_amdgcn_mfma_f32_16x16x32_f16(
                    aF[mt], bF[nt], acc[mt][nt], 0, 0, 0);
        __syncthreads();
    }

#pragma unroll
    for (int mt = 0; mt < 4; ++mt)
#pragma unroll
        for (int nt = 0; nt < 4; ++nt)
#pragma unroll
            for (int r = 0; r < 4; ++r) {
                int row = bm + waveM + mt * 16 + quad * 4 + r;
                int col = bn + waveN + nt * 16 + lrow;
                if (Cf16) Cf16[(size_t)row * N + col] = (_Float16)acc[mt][nt][r];
                else      Cf32[(size_t)row * N + col] = acc[mt][nt][r];
            }
}

// ---------------------------------------------------------------- RoPE + split q/k
__global__ __launch_bounds__(256) void rope_split(const _Float16* __restrict__ qkv,
                                                  const float* __restrict__ fc,
                                                  const float* __restrict__ fs,
                                                  _Float16* __restrict__ qh,
                                                  _Float16* __restrict__ kh) {
    int row = blockIdx.x;
    int b = row >> 11, t = row & 2047;
    const _Float16* src = qkv + (size_t)row * 3072;
    for (int p = threadIdx.x; p < 512; p += 256) {
        int h = p >> 5, j = p & 31;
        float c = fc[t * 32 + j], s = fs[t * 32 + j];
        size_t o = ((size_t)(b * 16 + h) * 2048 + t) * 64 + 2 * j;
        {
            half2v xin = *(const half2v*)&src[h * 64 + 2 * j];
            float x0 = (float)xin[0], x1 = (float)xin[1];
            half2v out = { (_Float16)(x0 * c - x1 * s), (_Float16)(x0 * s + x1 * c) };
            *(half2v*)&qh[o] = out;
        }
        {
            half2v xin = *(const half2v*)&src[1024 + h * 64 + 2 * j];
            float x0 = (float)xin[0], x1 = (float)xin[1];
            half2v out = { (_Float16)(x0 * c - x1 * s), (_Float16)(x0 * s + x1 * c) };
            *(half2v*)&kh[o] = out;
        }
    }
}

// ---------------------------------------------------------------- V transpose
__global__ __launch_bounds__(256) void vtrans(const _Float16* __restrict__ qkv,
                                              _Float16* __restrict__ vt) {
    __shared__ _Float16 s[64][72];
    int bh = blockIdx.y, t0 = blockIdx.x * 64;
    int b = bh >> 4, h = bh & 15;
    int c = threadIdx.x & 63, r4 = threadIdx.x >> 6;
    const _Float16* src = qkv + 2048 + h * 64;
    for (int rr = 0; rr < 64; rr += 4) {
        int t = t0 + rr + r4;
        s[rr + r4][c] = src[(size_t)(b * 2048 + t) * 3072 + c];
    }
    __syncthreads();
    for (int rr = 0; rr < 64; rr += 4) {
        int hd = rr + r4;
        vt[((size_t)bh * 64 + hd) * 2048 + t0 + c] = s[c][hd];
    }
}

// ---------------------------------------------------------------- flash attention, paired tiles
// Q,K: [32][2048][64], Vt: [32][64][2048], Y: [4096][1024]  (all f16)
// Block = pair of q-tiles (p, 31-p) for one (b,h): uniform 33 compute-units/block.
// S^T trick: per-lane q-row stats (q = lane&15), packed b64 P stores.
// Staging via global_load_lds: destination is forced linear (base+lane*16), so the
// XOR swizzle is realized by permuting the SOURCE chunk index instead.
__global__ __launch_bounds__(256) void attn_pair(const _Float16* __restrict__ Q,
                                                 const _Float16* __restrict__ Kk,
                                                 const _Float16* __restrict__ Vt,
                                                 _Float16* __restrict__ Y) {
    __shared__ __align__(16) _Float16 sK[2][64 * 64];   // [buf][key][hd] xor-swizzled
    __shared__ __align__(16) _Float16 sV[2][64 * 64];   // [buf][hd][key] xor-swizzled
    __shared__ __align__(16) _Float16 sP[2][64 * 72];   // [tile][qrow][key] padded

    const int bh = blockIdx.y, b = bh >> 4, h = bh & 15;
    const int p = blockIdx.x;                 // 0..15
    const int tid = threadIdx.x;
    const int wave = tid >> 6, lane = tid & 63;
    const int lq = lane & 15, quad = lane >> 4;
    const int qt0 = p, qt1 = 31 - p;
    const int nst = qt1 + 1;                  // staged k-tiles

    const _Float16* Kbase = Kk + (size_t)bh * 2048 * 64;
    const _Float16* Vbase = Vt + (size_t)bh * 64 * 2048;

    // Q fragments; scale = 1/sqrt(64) * log2(e)  (exp computed in base-2 domain)
    const _Float16 qscale = (_Float16)(0.125f * 1.44269504f);
    half8 qF[2][2];
    {
        const _Float16* Qp0 = Q + ((size_t)bh * 2048 + qt0 * 64 + wave * 16 + lq) * 64;
        const _Float16* Qp1 = Q + ((size_t)bh * 2048 + qt1 * 64 + wave * 16 + lq) * 64;
#pragma unroll
        for (int ks = 0; ks < 2; ++ks) {
            qF[0][ks] = (*(const half8*)(Qp0 + ks * 32 + quad * 8)) * qscale;
            qF[1][ks] = (*(const half8*)(Qp1 + ks * 32 + quad * 8)) * qscale;
        }
    }

    floatx4 O[2][4] = {};
    float m_i[2] = { -INFINITY, -INFINITY };
    float l_i[2] = { 0.f, 0.f };

    // LDS slot s (linear, forced by gld) holds global chunk (s&7)^(row&7), row=s>>3.
    // Read side un-swizzles with ^(row&7) -> recovers desired chunk.
    auto stage = [&](int bufi, int kt) {
        const _Float16* kb = Kbase + (size_t)kt * 64 * 64;
        const _Float16* vb = Vbase + kt * 64;
        _Float16* dK = sK[bufi];
        _Float16* dV = sV[bufi];
#pragma unroll
        for (int hlf = 0; hlf < 2; ++hlf) {
            int s = tid + hlf * 256;
            int row = s >> 3;                        // key
            int ccg = (s & 7) ^ (row & 7);
            gld16(kb + row * 64 + ccg * 8, dK + s * 8);
        }
#pragma unroll
        for (int hlf = 0; hlf < 2; ++hlf) {
            int s = tid + hlf * 256;
            int row = s >> 3;                        // hd
            int ccg = (s & 7) ^ (row & 7);
            gld16(vb + (size_t)row * 2048 + ccg * 8, dV + s * 8);
        }
    };

    auto compute_tile = [&](int t, int qt, int kti, int bufi) {
        const _Float16* bK = sK[bufi];
        const _Float16* bV = sV[bufi];
        // S^T = K * Q^T : D col = lane&15 = q, row = quad*4+r = key
        floatx4 St[4];
#pragma unroll
        for (int kt4 = 0; kt4 < 4; ++kt4) {
            floatx4 s = {};
#pragma unroll
            for (int ks = 0; ks < 2; ++ks) {
                half8 kf = *(const half8*)&bK[(kt4 * 16 + lq) * 64 +
                                              (((ks * 4 + quad) ^ (lq & 7)) * 8)];
                s = __builtin_amdgcn_mfma_f32_16x16x32_f16(kf, qF[t][ks], s, 0, 0, 0);
            }
            St[kt4] = s;
        }
        if (kti == qt) {   // diagonal: mask key > q
#pragma unroll
            for (int kt4 = 0; kt4 < 4; ++kt4)
#pragma unroll
                for (int r = 0; r < 4; ++r)
                    if (kt4 * 16 + quad * 4 + r > wave * 16 + lq) St[kt4][r] = -1e30f;
        }
        // per-lane row stats (q = lane&15); quads hold disjoint keys -> xor 16,32
        float mt = fmaxf(fmaxf(fmaxf(St[0][0], St[0][1]), fmaxf(St[0][2], St[0][3])),
                   fmaxf(fmaxf(fmaxf(St[1][0], St[1][1]), fmaxf(St[1][2], St[1][3])),
                   fmaxf(fmaxf(fmaxf(St[2][0], St[2][1]), fmaxf(St[2][2], St[2][3])),
                         fmaxf(fmaxf(St[3][0], St[3][1]), fmaxf(St[3][2], St[3][3])))));
        mt = fmaxf(mt, __shfl_xor(mt, 16));
        mt = fmaxf(mt, __shfl_xor(mt, 32));
        float mn = fmaxf(m_i[t], mt);
        float alpha = __builtin_amdgcn_exp2f(m_i[t] - mn);
        m_i[t] = mn;
#pragma unroll
        for (int kt4 = 0; kt4 < 4; ++kt4)
#pragma unroll
            for (int r = 0; r < 4; ++r)
                St[kt4][r] = __builtin_amdgcn_exp2f(St[kt4][r] - mn);
        float rs = (St[0][0] + St[0][1] + St[0][2] + St[0][3])
                 + (St[1][0] + St[1][1] + St[1][2] + St[1][3])
                 + (St[2][0] + St[2][1] + St[2][2] + St[2][3])
                 + (St[3][0] + St[3][1] + St[3][2] + St[3][3]);
        rs += __shfl_xor(rs, 16);
        rs += __shfl_xor(rs, 32);
        l_i[t] = l_i[t] * alpha + rs;

        // P -> LDS: row q = wave*16+lq, packed 4-key chunks (b64 stores)
        _Float16* pw = (_Float16*)&sP[t][(wave * 16 + lq) * 72];
#pragma unroll
        for (int kt4 = 0; kt4 < 4; ++kt4) {
            half4v pk = { (_Float16)St[kt4][0], (_Float16)St[kt4][1],
                          (_Float16)St[kt4][2], (_Float16)St[kt4][3] };
            *(half4v*)(pw + kt4 * 16 + quad * 4) = pk;
        }
        // rescale O (rows q = quad*4+r): broadcast alpha from lane with lane&15 == quad*4+r
#pragma unroll
        for (int r = 0; r < 4; ++r) {
            float ar = __shfl(alpha, (lane & 48) | (quad * 4 + r));
            O[t][0][r] *= ar; O[t][1][r] *= ar; O[t][2][r] *= ar; O[t][3][r] *= ar;
        }
        // O += P V : A = P (m=q), B = V^T (n=hd)
        half8 aP[2];
#pragma unroll
        for (int ks = 0; ks < 2; ++ks)
            aP[ks] = *(const half8*)(pw + ks * 32 + quad * 8);
#pragma unroll
        for (int nt = 0; nt < 4; ++nt)
#pragma unroll
            for (int ks = 0; ks < 2; ++ks) {
                half8 vf = *(const half8*)&bV[(nt * 16 + lq) * 64 +
                                              (((ks * 4 + quad) ^ (lq & 7)) * 8)];
                O[t][nt] = __builtin_amdgcn_mfma_f32_16x16x32_f16(aP[ks], vf, O[t][nt], 0, 0, 0);
            }
    };

    stage(0, 0);
    __syncthreads();
    for (int it = 0; it < nst; ++it) {
        int cur = it & 1;
        if (it + 1 < nst) stage(cur ^ 1, it + 1);   // prefetch next tile
        if (it <= qt0) compute_tile(0, qt0, it, cur);
        compute_tile(1, qt1, it, cur);
        __syncthreads();
    }

    // epilogue
#pragma unroll
    for (int t = 0; t < 2; ++t) {
        float invl = 1.0f / l_i[t];
        int qt = t ? qt1 : qt0;
#pragma unroll
        for (int r = 0; r < 4; ++r) {
            float iv = __shfl(invl, (lane & 48) | (quad * 4 + r));
            int q = qt * 64 + wave * 16 + quad * 4 + r;
            size_t rowoff = ((size_t)b * 2048 + q) * 1024 + h * 64;
#pragma unroll
            for (int nt = 0; nt < 4; ++nt)
                Y[rowoff + nt * 16 + lq] = (_Float16)(O[t][nt][r] * iv);
        }
    }
}

// ---------------------------------------------------------------- launch
extern "C" void kernel_launch(void* const* d_in, const int* in_sizes, int n_in,
                              void* d_out, int out_size, void* d_ws, size_t ws_size,
                              hipStream_t stream) {
    const float* x     = (const float*)d_in[0];
    const float* wqkv  = (const float*)d_in[1];
    const float* wproj = (const float*)d_in[2];
    const float* fc    = (const float*)d_in[3];
    const float* fs    = (const float*)d_in[4];
    float* out = (float*)d_out;

    char* ws = (char*)d_ws;
    _Float16* xh   = (_Float16*)(ws);                       // 8 MB  (reused as yh)
    _Float16* wqT  = (_Float16*)(ws + ((size_t)8  << 20));  // 6 MB
    _Float16* wpT  = (_Float16*)(ws + ((size_t)14 << 20));  // 2 MB
    _Float16* qkvh = (_Float16*)(ws + ((size_t)16 << 20));  // 24 MB
    _Float16* qh   = (_Float16*)(ws + ((size_t)40 << 20));  // 8 MB
    _Float16* kh   = (_Float16*)(ws + ((size_t)48 << 20));  // 8 MB
    _Float16* vt   = (_Float16*)(ws + ((size_t)56 << 20));  // 8 MB
    _Float16* yh   = xh;   // x dead after gemm1

    conv_x_kernel<<<4096, 256, 0, stream>>>(x, xh);
    transpose_f32f16<<<dim3(48, 16), 256, 0, stream>>>(wqkv, wqT, 1024, 3072);
    transpose_f32f16<<<dim3(16, 16), 256, 0, stream>>>(wproj, wpT, 1024, 1024);
    gemm_tn<<<dim3(32, 24), 256, 0, stream>>>(xh, wqT, qkvh, nullptr, 4096, 3072, 1024);
    rope_split<<<4096, 256, 0, stream>>>(qkvh, fc, fs, qh, kh);
    vtrans<<<dim3(32, 32), 256, 0, stream>>>(qkvh, vt);
    attn_pair<<<dim3(16, 32), 256, 0, stream>>>(qh, kh, vt, yh);
    gemm_tn<<<dim3(32, 8), 256, 0, stream>>>(yh, wpT, nullptr, out, 4096, 1024, 1024);
}